// Round 2
// baseline (1041.341 us; speedup 1.0000x reference)
//
#include <hip/hip_runtime.h>

// GCN 5-layer, no inter-layer nonlinearity -> collapses to rank-6 outer product:
// out = relu( a5*w_all^T + u4*c1^T + u3*c2^T + u2*c3^T + u1*c4^T + 1*b5^T )
// a_k = S^k x (x is N x 1), u_k = S^k 1, S = D^-1/2 (A + I) D^-1/2 (weighted).
// a/u chains are paired into float2 so only 5 scatter passes over edges run.
// NOTE: edge_index arrives as int32 (harness converts int64 -> int32).

#define TB 256

__global__ __launch_bounds__(TB) void k_zero(float* __restrict__ p, int n) {
    int v = blockIdx.x * TB + threadIdx.x;
    if (v < n) p[v] = 0.0f;
}

__global__ __launch_bounds__(TB) void k_deg(const int* __restrict__ dst,
                                            const float* __restrict__ w,
                                            float* __restrict__ deg, int E) {
    int e = blockIdx.x * TB + threadIdx.x;
    if (e >= E) return;
    unsafeAtomicAdd(&deg[dst[e]], w[e]);
}

__global__ __launch_bounds__(TB) void k_dinv(float* __restrict__ deg_dinv,
                                             float* __restrict__ self_norm, int n) {
    int v = blockIdx.x * TB + threadIdx.x;
    if (v >= n) return;
    float di = rsqrtf(deg_dinv[v] + 1.0f);  // deg >= 1 always (self loop weight 1)
    deg_dinv[v] = di;
    self_norm[v] = di * di;
}

__global__ __launch_bounds__(TB) void k_norm(const int* __restrict__ src,
                                             const int* __restrict__ dst,
                                             const float* __restrict__ w,
                                             const float* __restrict__ dinv,
                                             float* __restrict__ norm, int E) {
    int e = blockIdx.x * TB + threadIdx.x;
    if (e >= E) return;
    norm[e] = dinv[src[e]] * w[e] * dinv[dst[e]];
}

// Collapse the weight chain on-device (tiny, 1 block).
// coef[0]=W1*W2*W3*W4*W5 (row0, since x is Nx1 and W1 is 1x20),
// coef[1]=b1*W2..W5, coef[2]=b2*W3..W5, coef[3]=b3*W4*W5, coef[4]=b4*W5
__global__ void k_chains(const float* __restrict__ W1, const float* __restrict__ b1,
                         const float* __restrict__ W2, const float* __restrict__ b2,
                         const float* __restrict__ W3, const float* __restrict__ b3,
                         const float* __restrict__ W4, const float* __restrict__ b4,
                         const float* __restrict__ W5, float* __restrict__ coef) {
    __shared__ float A[5][112];
    __shared__ float B[5][112];
    int t = threadIdx.x;  // 128 threads
    if (t < 20) { A[0][t] = W1[t]; A[1][t] = b1[t]; }
    __syncthreads();
    if (t < 40) {  // x W2 : 20 -> 40, chains 0,1
        for (int c = 0; c < 2; ++c) {
            float acc = 0.f;
            for (int k = 0; k < 20; ++k) acc += A[c][k] * W2[k * 40 + t];
            B[c][t] = acc;
        }
        B[2][t] = b2[t];
    }
    __syncthreads();
    if (t < 60) {  // x W3 : 40 -> 60, chains 0..2
        for (int c = 0; c < 3; ++c) {
            float acc = 0.f;
            for (int k = 0; k < 40; ++k) acc += B[c][k] * W3[k * 60 + t];
            A[c][t] = acc;
        }
        A[3][t] = b3[t];
    }
    __syncthreads();
    if (t < 80) {  // x W4 : 60 -> 80, chains 0..3
        for (int c = 0; c < 4; ++c) {
            float acc = 0.f;
            for (int k = 0; k < 60; ++k) acc += A[c][k] * W4[k * 80 + t];
            B[c][t] = acc;
        }
        B[4][t] = b4[t];
    }
    __syncthreads();
    if (t < 100) {  // x W5 : 80 -> 100, chains 0..4
        for (int c = 0; c < 5; ++c) {
            float acc = 0.f;
            for (int k = 0; k < 80; ++k) acc += B[c][k] * W5[k * 100 + t];
            coef[c * 100 + t] = acc;
        }
    }
}

// out[v] = self_norm[v] * in[v]   (self-loop term; also initializes the atomic target)
template <bool FIRST>
__global__ __launch_bounds__(TB) void k_mv_init(const float* __restrict__ x,
                                                const float2* __restrict__ in,
                                                const float* __restrict__ self_norm,
                                                float2* __restrict__ out, int n) {
    int v = blockIdx.x * TB + threadIdx.x;
    if (v >= n) return;
    float sn = self_norm[v];
    float2 o;
    if (FIRST) { o.x = sn * x[v]; o.y = sn; }          // channels: (x, ones)
    else       { float2 iv = in[v]; o.x = sn * iv.x; o.y = sn * iv.y; }
    out[v] = o;
}

// out[dst] += norm[e] * in[src]  (both channels)
template <bool FIRST>
__global__ __launch_bounds__(TB) void k_mv_scatter(const float* __restrict__ x,
                                                   const float2* __restrict__ in,
                                                   const int* __restrict__ src,
                                                   const int* __restrict__ dst,
                                                   const float* __restrict__ norm,
                                                   float2* __restrict__ out, int E) {
    int e = blockIdx.x * TB + threadIdx.x;
    if (e >= E) return;
    int s = src[e];
    float nrm = norm[e];
    float vx, vy;
    if (FIRST) { vx = x[s]; vy = 1.0f; }
    else       { float2 iv = in[s]; vx = iv.x; vy = iv.y; }
    float* o = (float*)(out + dst[e]);
    unsafeAtomicAdd(o,     nrm * vx);
    unsafeAtomicAdd(o + 1, nrm * vy);
}

// out[v,j] = relu(a5[v]*coef0[j] + u4[v]*coef1[j] + u3[v]*coef2[j]
//                 + u2[v]*coef3[j] + u1[v]*coef4[j] + b5[j])
__global__ __launch_bounds__(TB) void k_final(const float2* __restrict__ s1,
                                              const float2* __restrict__ s2,
                                              const float2* __restrict__ s3,
                                              const float2* __restrict__ s4,
                                              const float2* __restrict__ s5,
                                              const float* __restrict__ coef,
                                              const float* __restrict__ b5,
                                              float* __restrict__ out, int n) {
    int idx = blockIdx.x * TB + threadIdx.x;
    if (idx >= n * 100) return;
    int v = idx / 100;
    int j = idx - v * 100;
    float r = b5[j]
            + s5[v].x * coef[j]
            + s4[v].y * coef[100 + j]
            + s3[v].y * coef[200 + j]
            + s2[v].y * coef[300 + j]
            + s1[v].y * coef[400 + j];
    out[idx] = fmaxf(r, 0.0f);
}

extern "C" void kernel_launch(void* const* d_in, const int* in_sizes, int n_in,
                              void* d_out, int out_size, void* d_ws, size_t ws_size,
                              hipStream_t stream) {
    const float* x  = (const float*)d_in[0];
    const int*   ei = (const int*)d_in[1];     // int32: [2, E] flattened
    const float* w  = (const float*)d_in[2];
    const float* W1 = (const float*)d_in[3];  const float* b1 = (const float*)d_in[4];
    const float* W2 = (const float*)d_in[5];  const float* b2 = (const float*)d_in[6];
    const float* W3 = (const float*)d_in[7];  const float* b3 = (const float*)d_in[8];
    const float* W4 = (const float*)d_in[9];  const float* b4 = (const float*)d_in[10];
    const float* W5 = (const float*)d_in[11]; const float* b5 = (const float*)d_in[12];

    const int n = in_sizes[0];   // 100000 (x is N x 1)
    const int E = in_sizes[2];   // 1600000
    const int* src = ei;
    const int* dst = ei + E;

    char* ws = (char*)d_ws;
    size_t off = 0;
    auto alloc = [&](size_t bytes) -> void* {
        void* p = ws + off;
        off += (bytes + 255) & ~(size_t)255;
        return p;
    };
    float* deg       = (float*)alloc((size_t)n * 4);  // becomes dinv in-place
    float* self_norm = (float*)alloc((size_t)n * 4);
    float* norm      = (float*)alloc((size_t)E * 4);
    float2* s[5];
    for (int i = 0; i < 5; ++i) s[i] = (float2*)alloc((size_t)n * 8);
    float* coef = (float*)alloc(512 * 4);

    const int gE = (E + TB - 1) / TB;
    const int gN = (n + TB - 1) / TB;

    k_zero<<<gN, TB, 0, stream>>>(deg, n);
    k_deg <<<gE, TB, 0, stream>>>(dst, w, deg, E);
    k_dinv<<<gN, TB, 0, stream>>>(deg, self_norm, n);
    k_norm<<<gE, TB, 0, stream>>>(src, dst, w, deg, norm, E);
    k_chains<<<1, 128, 0, stream>>>(W1, b1, W2, b2, W3, b3, W4, b4, W5, coef);

    // paired (a, u) chains: s[k] = S^{k+1} (x, 1)
    k_mv_init<true>   <<<gN, TB, 0, stream>>>(x, nullptr, self_norm, s[0], n);
    k_mv_scatter<true><<<gE, TB, 0, stream>>>(x, nullptr, src, dst, norm, s[0], E);
    for (int k = 1; k < 5; ++k) {
        k_mv_init<false>   <<<gN, TB, 0, stream>>>(nullptr, s[k - 1], self_norm, s[k], n);
        k_mv_scatter<false><<<gE, TB, 0, stream>>>(nullptr, s[k - 1], src, dst, norm, s[k], E);
    }

    const int tot = n * 100;
    k_final<<<(tot + TB - 1) / TB, TB, 0, stream>>>(s[0], s[1], s[2], s[3], s[4],
                                                    coef, b5, (float*)d_out, n);
}

// Round 3
// 331.574 us; speedup vs baseline: 3.1406x; 3.1406x over previous
//
#include <hip/hip_runtime.h>

// GCN 5-layer, no inter-layer nonlinearity -> collapses to rank-6 outer product:
// out = relu( a5*c0^T + u4*c1^T + u3*c2^T + u2*c3^T + u1*c4^T + 1*b5^T )
// a_k = S^k x, u_k = S^k 1, S = D^-1/2 (A + I) D^-1/2 (weighted), x is N x 1.
// R3: atomic scatter (19 G atomics/s memory-side RMW bound) replaced by a
// per-launch CSR build (1 int atomic/edge) + 5 atomic-free gather passes.

#define TB 256

// ---------------- small shared kernels ----------------

__global__ __launch_bounds__(TB) void k_zero(int* __restrict__ p, int n) {
    int v = blockIdx.x * TB + threadIdx.x;
    if (v < n) p[v] = 0;
}

// coef[0]=W1*W2*W3*W4*W5 row0, coef[1]=b1*W2..W5, coef[2]=b2*W3..W5,
// coef[3]=b3*W4*W5, coef[4]=b4*W5   (tiny, 1 block)
__global__ void k_chains(const float* __restrict__ W1, const float* __restrict__ b1,
                         const float* __restrict__ W2, const float* __restrict__ b2,
                         const float* __restrict__ W3, const float* __restrict__ b3,
                         const float* __restrict__ W4, const float* __restrict__ b4,
                         const float* __restrict__ W5, float* __restrict__ coef) {
    __shared__ float A[5][112];
    __shared__ float B[5][112];
    int t = threadIdx.x;  // 128 threads
    if (t < 20) { A[0][t] = W1[t]; A[1][t] = b1[t]; }
    __syncthreads();
    if (t < 40) {
        for (int c = 0; c < 2; ++c) {
            float acc = 0.f;
            for (int k = 0; k < 20; ++k) acc += A[c][k] * W2[k * 40 + t];
            B[c][t] = acc;
        }
        B[2][t] = b2[t];
    }
    __syncthreads();
    if (t < 60) {
        for (int c = 0; c < 3; ++c) {
            float acc = 0.f;
            for (int k = 0; k < 40; ++k) acc += B[c][k] * W3[k * 60 + t];
            A[c][t] = acc;
        }
        A[3][t] = b3[t];
    }
    __syncthreads();
    if (t < 80) {
        for (int c = 0; c < 4; ++c) {
            float acc = 0.f;
            for (int k = 0; k < 60; ++k) acc += A[c][k] * W4[k * 80 + t];
            B[c][t] = acc;
        }
        B[4][t] = b4[t];
    }
    __syncthreads();
    if (t < 100) {
        for (int c = 0; c < 5; ++c) {
            float acc = 0.f;
            for (int k = 0; k < 80; ++k) acc += B[c][k] * W5[k * 100 + t];
            coef[c * 100 + t] = acc;
        }
    }
}

// out[q] covers 4 output floats; row = 100 floats (100 % 4 == 0).
__global__ __launch_bounds__(TB) void k_final4(const float2* __restrict__ s1,
                                               const float2* __restrict__ s2,
                                               const float2* __restrict__ s3,
                                               const float2* __restrict__ s4,
                                               const float2* __restrict__ s5,
                                               const float* __restrict__ coef,
                                               const float* __restrict__ b5,
                                               float4* __restrict__ out, int n) {
    int q = blockIdx.x * TB + threadIdx.x;
    if (q >= n * 25) return;
    int v = q / 25;
    int j = (q - v * 25) * 4;
    float a5 = s5[v].x, u4 = s4[v].y, u3 = s3[v].y, u2 = s2[v].y, u1 = s1[v].y;
    float4 r;
    float* rp = (float*)&r;
#pragma unroll
    for (int k = 0; k < 4; ++k) {
        int jj = j + k;
        float val = b5[jj]
                  + a5 * coef[jj]
                  + u4 * coef[100 + jj]
                  + u3 * coef[200 + jj]
                  + u2 * coef[300 + jj]
                  + u1 * coef[400 + jj];
        rp[k] = fmaxf(val, 0.0f);
    }
    out[q] = r;
}

// ---------------- CSR path ----------------

__global__ __launch_bounds__(TB) void k_count(const int* __restrict__ dst,
                                              int* __restrict__ cnt,
                                              int* __restrict__ pos, int E) {
    int e = blockIdx.x * TB + threadIdx.x;
    if (e >= E) return;
    pos[e] = atomicAdd(&cnt[dst[e]], 1);
}

// in-place per-block exclusive scan of cnt; block totals to bsum
__global__ __launch_bounds__(TB) void k_scan1(int* __restrict__ cnt,
                                              int* __restrict__ bsum, int n) {
    __shared__ int tmp[TB];
    int i = blockIdx.x * TB + threadIdx.x;
    int v = (i < n) ? cnt[i] : 0;
    tmp[threadIdx.x] = v;
    __syncthreads();
    for (int off = 1; off < TB; off <<= 1) {
        int t = (threadIdx.x >= off) ? tmp[threadIdx.x - off] : 0;
        __syncthreads();
        tmp[threadIdx.x] += t;
        __syncthreads();
    }
    if (i < n) cnt[i] = tmp[threadIdx.x] - v;  // exclusive within block
    if (threadIdx.x == TB - 1) bsum[blockIdx.x] = tmp[TB - 1];
}

// exclusive scan of block sums (nb <= 512), single block
__global__ void k_scan2(int* __restrict__ bsum, int nb) {
    __shared__ int tmp[512];
    int x = threadIdx.x;
    int v = (x < nb) ? bsum[x] : 0;
    tmp[x] = v;
    __syncthreads();
    for (int off = 1; off < 512; off <<= 1) {
        int t = (x >= off) ? tmp[x - off] : 0;
        __syncthreads();
        tmp[x] += t;
        __syncthreads();
    }
    if (x < nb) bsum[x] = tmp[x] - v;
}

__global__ __launch_bounds__(TB) void k_scan3(const int* __restrict__ cnt,
                                              const int* __restrict__ bsum,
                                              int* __restrict__ rowptr, int n, int E) {
    int i = blockIdx.x * TB + threadIdx.x;
    if (i < n) rowptr[i] = cnt[i] + bsum[i >> 8];  // TB == 256
    if (i == 0) rowptr[n] = E;
}

__global__ __launch_bounds__(TB) void k_place(const int* __restrict__ src,
                                              const int* __restrict__ dst,
                                              const float* __restrict__ w,
                                              const int* __restrict__ pos,
                                              const int* __restrict__ rowptr,
                                              int2* __restrict__ payload, int E) {
    int e = blockIdx.x * TB + threadIdx.x;
    if (e >= E) return;
    int slot = rowptr[dst[e]] + pos[e];
    payload[slot] = make_int2(src[e], __float_as_int(w[e]));
}

// weighted in-degree by row gather (no atomics), then dinv / self-norm
__global__ __launch_bounds__(TB) void k_rowstats(const int* __restrict__ rowptr,
                                                 const int2* __restrict__ payload,
                                                 float* __restrict__ dinv,
                                                 float* __restrict__ selfn, int n) {
    int v = blockIdx.x * TB + threadIdx.x;
    if (v >= n) return;
    int b = rowptr[v], e = rowptr[v + 1];
    float deg = 0.f;
    for (int i = b; i < e; ++i) deg += __int_as_float(payload[i].y);
    float di = rsqrtf(deg + 1.0f);  // deg >= 0, +1 self loop
    dinv[v] = di;
    selfn[v] = di * di;
}

// fold dinv[src] into payload weight: nw = dinv[src] * w
__global__ __launch_bounds__(TB) void k_prep(int2* __restrict__ payload,
                                             const float* __restrict__ dinv, int E) {
    int i = blockIdx.x * TB + threadIdx.x;
    if (i >= E) return;
    int2 p = payload[i];
    float nw = __int_as_float(p.y) * dinv[p.x];
    payload[i] = make_int2(p.x, __float_as_int(nw));
}

// out[v] = dinv[v] * sum_row nw * in[src] + selfn[v] * in[v]   (both channels)
template <bool FIRST>
__global__ __launch_bounds__(TB) void k_gather(const float* __restrict__ x,
                                               const float2* __restrict__ in,
                                               const int* __restrict__ rowptr,
                                               const int2* __restrict__ payload,
                                               const float* __restrict__ dinv,
                                               const float* __restrict__ selfn,
                                               float2* __restrict__ out, int n) {
    int v = blockIdx.x * TB + threadIdx.x;
    if (v >= n) return;
    int b = rowptr[v], e = rowptr[v + 1];
    float ax = 0.f, ay = 0.f;
    for (int i = b; i < e; ++i) {
        int2 p = payload[i];
        float nw = __int_as_float(p.y);
        float vx, vy;
        if (FIRST) { vx = x[p.x]; vy = 1.0f; }
        else       { float2 iv = in[p.x]; vx = iv.x; vy = iv.y; }
        ax = fmaf(nw, vx, ax);
        ay = fmaf(nw, vy, ay);
    }
    float dv = dinv[v], sf = selfn[v];
    float ivx, ivy;
    if (FIRST) { ivx = x[v]; ivy = 1.0f; }
    else       { float2 iv = in[v]; ivx = iv.x; ivy = iv.y; }
    out[v] = make_float2(fmaf(dv, ax, sf * ivx), fmaf(dv, ay, sf * ivy));
}

// ---------------- fallback (R2 atomic-scatter path, known-good) ----------------

__global__ __launch_bounds__(TB) void k_deg(const int* __restrict__ dst,
                                            const float* __restrict__ w,
                                            float* __restrict__ deg, int E) {
    int e = blockIdx.x * TB + threadIdx.x;
    if (e >= E) return;
    unsafeAtomicAdd(&deg[dst[e]], w[e]);
}

__global__ __launch_bounds__(TB) void k_dinv(float* __restrict__ deg_dinv,
                                             float* __restrict__ self_norm, int n) {
    int v = blockIdx.x * TB + threadIdx.x;
    if (v >= n) return;
    float di = rsqrtf(deg_dinv[v] + 1.0f);
    deg_dinv[v] = di;
    self_norm[v] = di * di;
}

__global__ __launch_bounds__(TB) void k_norm(const int* __restrict__ src,
                                             const int* __restrict__ dst,
                                             const float* __restrict__ w,
                                             const float* __restrict__ dinv,
                                             float* __restrict__ norm, int E) {
    int e = blockIdx.x * TB + threadIdx.x;
    if (e >= E) return;
    norm[e] = dinv[src[e]] * w[e] * dinv[dst[e]];
}

template <bool FIRST>
__global__ __launch_bounds__(TB) void k_mv_init(const float* __restrict__ x,
                                                const float2* __restrict__ in,
                                                const float* __restrict__ self_norm,
                                                float2* __restrict__ out, int n) {
    int v = blockIdx.x * TB + threadIdx.x;
    if (v >= n) return;
    float sn = self_norm[v];
    float2 o;
    if (FIRST) { o.x = sn * x[v]; o.y = sn; }
    else       { float2 iv = in[v]; o.x = sn * iv.x; o.y = sn * iv.y; }
    out[v] = o;
}

template <bool FIRST>
__global__ __launch_bounds__(TB) void k_mv_scatter(const float* __restrict__ x,
                                                   const float2* __restrict__ in,
                                                   const int* __restrict__ src,
                                                   const int* __restrict__ dst,
                                                   const float* __restrict__ norm,
                                                   float2* __restrict__ out, int E) {
    int e = blockIdx.x * TB + threadIdx.x;
    if (e >= E) return;
    int s = src[e];
    float nrm = norm[e];
    float vx, vy;
    if (FIRST) { vx = x[s]; vy = 1.0f; }
    else       { float2 iv = in[s]; vx = iv.x; vy = iv.y; }
    float* o = (float*)(out + dst[e]);
    unsafeAtomicAdd(o,     nrm * vx);
    unsafeAtomicAdd(o + 1, nrm * vy);
}

// ---------------- launch ----------------

extern "C" void kernel_launch(void* const* d_in, const int* in_sizes, int n_in,
                              void* d_out, int out_size, void* d_ws, size_t ws_size,
                              hipStream_t stream) {
    const float* x  = (const float*)d_in[0];
    const int*   ei = (const int*)d_in[1];     // int32: [2, E] flattened
    const float* w  = (const float*)d_in[2];
    const float* W1 = (const float*)d_in[3];  const float* b1 = (const float*)d_in[4];
    const float* W2 = (const float*)d_in[5];  const float* b2 = (const float*)d_in[6];
    const float* W3 = (const float*)d_in[7];  const float* b3 = (const float*)d_in[8];
    const float* W4 = (const float*)d_in[9];  const float* b4 = (const float*)d_in[10];
    const float* W5 = (const float*)d_in[11]; const float* b5 = (const float*)d_in[12];

    const int n = in_sizes[0];   // 100000
    const int E = in_sizes[2];   // 1600000
    const int* src = ei;
    const int* dst = ei + E;

    const int gE = (E + TB - 1) / TB;
    const int gN = (n + TB - 1) / TB;
    const int nb = gN;           // scan blocks (391 for n=100000)

    char* ws = (char*)d_ws;
    size_t off = 0;
    auto alloc = [&](size_t bytes) -> void* {
        void* p = ws + off;
        off += (bytes + 255) & ~(size_t)255;
        return p;
    };

    // CSR layout
    int*  cnt     = (int*)alloc((size_t)n * 4);
    int*  rowptr  = (int*)alloc((size_t)(n + 1) * 4);
    int*  bsum    = (int*)alloc((size_t)nb * 4);
    float* dinv   = (float*)alloc((size_t)n * 4);
    float* selfn  = (float*)alloc((size_t)n * 4);
    float* coef   = (float*)alloc(512 * 4);
    int2* payload = (int2*)alloc((size_t)E * 8);
    // pos region reused as the 5 chain buffers after k_place
    size_t posRegion = (size_t)E * 4;
    size_t sRegion   = (size_t)5 * n * 8;
    char* region = (char*)alloc(posRegion > sRegion ? posRegion : sRegion);
    int* pos = (int*)region;
    float2* s[5];
    for (int i = 0; i < 5; ++i) s[i] = (float2*)(region + (size_t)i * n * 8);
    size_t need_csr = off;

    const bool csr_ok = (need_csr <= ws_size) && (nb <= 512);

    if (csr_ok) {
        k_zero <<<gN, TB, 0, stream>>>(cnt, n);
        k_count<<<gE, TB, 0, stream>>>(dst, cnt, pos, E);
        k_scan1<<<nb, TB, 0, stream>>>(cnt, bsum, n);
        k_scan2<<<1, 512, 0, stream>>>(bsum, nb);
        k_scan3<<<gN, TB, 0, stream>>>(cnt, bsum, rowptr, n, E);
        k_place<<<gE, TB, 0, stream>>>(src, dst, w, pos, rowptr, payload, E);
        k_rowstats<<<gN, TB, 0, stream>>>(rowptr, payload, dinv, selfn, n);
        k_prep <<<gE, TB, 0, stream>>>(payload, dinv, E);
        k_chains<<<1, 128, 0, stream>>>(W1, b1, W2, b2, W3, b3, W4, b4, W5, coef);

        // s[k] = S^{k+1} (x, 1)   (pos region is dead after k_place)
        k_gather<true> <<<gN, TB, 0, stream>>>(x, nullptr, rowptr, payload, dinv, selfn, s[0], n);
        for (int k = 1; k < 5; ++k)
            k_gather<false><<<gN, TB, 0, stream>>>(nullptr, s[k - 1], rowptr, payload, dinv, selfn, s[k], n);
    } else {
        // R2 known-good atomic path, smaller footprint
        off = 0;
        float* deg       = (float*)alloc((size_t)n * 4);
        float* self_norm = (float*)alloc((size_t)n * 4);
        float* norm      = (float*)alloc((size_t)E * 4);
        for (int i = 0; i < 5; ++i) s[i] = (float2*)alloc((size_t)n * 8);
        coef = (float*)alloc(512 * 4);
        dinv = deg; selfn = self_norm;

        k_zero<<<gN, TB, 0, stream>>>((int*)deg, n);
        k_deg <<<gE, TB, 0, stream>>>(dst, w, deg, E);
        k_dinv<<<gN, TB, 0, stream>>>(deg, self_norm, n);
        k_norm<<<gE, TB, 0, stream>>>(src, dst, w, deg, norm, E);
        k_chains<<<1, 128, 0, stream>>>(W1, b1, W2, b2, W3, b3, W4, b4, W5, coef);

        k_mv_init<true>   <<<gN, TB, 0, stream>>>(x, nullptr, self_norm, s[0], n);
        k_mv_scatter<true><<<gE, TB, 0, stream>>>(x, nullptr, src, dst, norm, s[0], E);
        for (int k = 1; k < 5; ++k) {
            k_mv_init<false>   <<<gN, TB, 0, stream>>>(nullptr, s[k - 1], self_norm, s[k], n);
            k_mv_scatter<false><<<gE, TB, 0, stream>>>(nullptr, s[k - 1], src, dst, norm, s[k], E);
        }
    }

    const int tot4 = n * 25;  // n*100 floats as float4
    k_final4<<<(tot4 + TB - 1) / TB, TB, 0, stream>>>(s[0], s[1], s[2], s[3], s[4],
                                                      coef, b5, (float4*)d_out, n);
}

// Round 4
// 285.693 us; speedup vs baseline: 3.6450x; 1.1606x over previous
//
#include <hip/hip_runtime.h>

// GCN 5-layer, no inter-layer nonlinearity -> collapses to rank-6 outer product:
// out = relu( a5*c0^T + u4*c1^T + u3*c2^T + u2*c3^T + u1*c4^T + 1*b5^T )
// a_k = S^k x, u_k = S^k 1, S = D^-1/2 (A + I) D^-1/2 (weighted), x is N x 1.
//
// R4: global atomics are memory-side 32B RMWs on gfx950 (~24 G ops/s ceiling;
// WRITE_SIZE == ops*32B in R2/R3 profiles). Replace the atomic CSR build with
// an LDS-histogram counting sort at 128-node-bucket granularity, and replace
// per-node gather rows with per-bucket LDS float2 accumulation.

#define TB 256
#define BNODES 128          // nodes per bucket
#define CHB 256             // chunk blocks for hist/place

// ---------------- tiny dense kernels ----------------

// coef[0]=W1..W5 row0, coef[1]=b1*W2..W5, coef[2]=b2*W3..W5, coef[3]=b3*W4*W5, coef[4]=b4*W5
__global__ void k_chains(const float* __restrict__ W1, const float* __restrict__ b1,
                         const float* __restrict__ W2, const float* __restrict__ b2,
                         const float* __restrict__ W3, const float* __restrict__ b3,
                         const float* __restrict__ W4, const float* __restrict__ b4,
                         const float* __restrict__ W5, float* __restrict__ coef) {
    __shared__ float A[5][112];
    __shared__ float B[5][112];
    int t = threadIdx.x;  // 128 threads
    if (t < 20) { A[0][t] = W1[t]; A[1][t] = b1[t]; }
    __syncthreads();
    if (t < 40) {
        for (int c = 0; c < 2; ++c) {
            float acc = 0.f;
            for (int k = 0; k < 20; ++k) acc += A[c][k] * W2[k * 40 + t];
            B[c][t] = acc;
        }
        B[2][t] = b2[t];
    }
    __syncthreads();
    if (t < 60) {
        for (int c = 0; c < 3; ++c) {
            float acc = 0.f;
            for (int k = 0; k < 40; ++k) acc += B[c][k] * W3[k * 60 + t];
            A[c][t] = acc;
        }
        A[3][t] = b3[t];
    }
    __syncthreads();
    if (t < 80) {
        for (int c = 0; c < 4; ++c) {
            float acc = 0.f;
            for (int k = 0; k < 60; ++k) acc += A[c][k] * W4[k * 80 + t];
            B[c][t] = acc;
        }
        B[4][t] = b4[t];
    }
    __syncthreads();
    if (t < 100) {
        for (int c = 0; c < 5; ++c) {
            float acc = 0.f;
            for (int k = 0; k < 80; ++k) acc += B[c][k] * W5[k * 100 + t];
            coef[c * 100 + t] = acc;
        }
    }
}

__global__ __launch_bounds__(TB) void k_final4(const float2* __restrict__ s1,
                                               const float2* __restrict__ s2,
                                               const float2* __restrict__ s3,
                                               const float2* __restrict__ s4,
                                               const float2* __restrict__ s5,
                                               const float* __restrict__ coef,
                                               const float* __restrict__ b5,
                                               float4* __restrict__ out, int n) {
    int q = blockIdx.x * TB + threadIdx.x;
    if (q >= n * 25) return;
    int v = q / 25;
    int j = (q - v * 25) * 4;
    float a5 = s5[v].x, u4 = s4[v].y, u3 = s3[v].y, u2 = s2[v].y, u1 = s1[v].y;
    float4 r;
    float* rp = (float*)&r;
#pragma unroll
    for (int k = 0; k < 4; ++k) {
        int jj = j + k;
        float val = b5[jj]
                  + a5 * coef[jj]
                  + u4 * coef[100 + jj]
                  + u3 * coef[200 + jj]
                  + u2 * coef[300 + jj]
                  + u1 * coef[400 + jj];
        rp[k] = fmaxf(val, 0.0f);
    }
    out[q] = r;
}

// ---------------- LDS-histogram bucket sort ----------------

// histmat[bucket * CHB + blk] = #edges of chunk blk with dst in bucket
__global__ __launch_bounds__(TB) void k_hist(const int* __restrict__ dst,
                                             int* __restrict__ histmat,
                                             int E, int B, int chunk) {
    extern __shared__ int lhist[];  // B ints
    for (int j = threadIdx.x; j < B; j += TB) lhist[j] = 0;
    __syncthreads();
    int blk = blockIdx.x;
    int e0 = blk * chunk;
    int e1 = min(E, e0 + chunk);
    for (int i = e0 + threadIdx.x; i < e1; i += TB)
        atomicAdd(&lhist[dst[i] >> 7], 1);
    __syncthreads();
    for (int j = threadIdx.x; j < B; j += TB)
        histmat[j * CHB + blk] = lhist[j];
}

// in-place per-block exclusive scan; block totals to bsum (block i == bucket i row)
__global__ __launch_bounds__(TB) void k_scan1(int* __restrict__ cnt,
                                              int* __restrict__ bsum, int n) {
    __shared__ int tmp[TB];
    int i = blockIdx.x * TB + threadIdx.x;
    int v = (i < n) ? cnt[i] : 0;
    tmp[threadIdx.x] = v;
    __syncthreads();
    for (int off = 1; off < TB; off <<= 1) {
        int t = (threadIdx.x >= off) ? tmp[threadIdx.x - off] : 0;
        __syncthreads();
        tmp[threadIdx.x] += t;
        __syncthreads();
    }
    if (i < n) cnt[i] = tmp[threadIdx.x] - v;  // exclusive within block
    if (threadIdx.x == TB - 1) bsum[blockIdx.x] = tmp[TB - 1];
}

// single-block exclusive scan of bsum (nb <= 1024); bsum becomes bucket_start; bsum[nb] = E
__global__ void k_scan2(int* __restrict__ bsum, int nb, int E) {
    __shared__ int tmp[1024];
    int x = threadIdx.x;
    int v = (x < nb) ? bsum[x] : 0;
    tmp[x] = v;
    __syncthreads();
    for (int off = 1; off < 1024; off <<= 1) {
        int t = (x >= off) ? tmp[x - off] : 0;
        __syncthreads();
        tmp[x] += t;
        __syncthreads();
    }
    if (x < nb) bsum[x] = tmp[x] - v;
    if (x == 0) bsum[nb] = E;
}

// histmat[i] += bucket_start[i >> 8]   (CHB == 256)
__global__ __launch_bounds__(TB) void k_scan3(int* __restrict__ histmat,
                                              const int* __restrict__ bsum, int n) {
    int i = blockIdx.x * TB + threadIdx.x;
    if (i < n) histmat[i] += bsum[i >> 8];
}

// payload[slot] = { src | (dst&127)<<17 , w }   grouped by bucket
__global__ __launch_bounds__(TB) void k_bplace(const int* __restrict__ src,
                                               const int* __restrict__ dst,
                                               const float* __restrict__ w,
                                               const int* __restrict__ histmat,
                                               int2* __restrict__ payload,
                                               int E, int B, int chunk) {
    extern __shared__ int lcur[];  // B ints
    int blk = blockIdx.x;
    for (int j = threadIdx.x; j < B; j += TB) lcur[j] = histmat[j * CHB + blk];
    __syncthreads();
    int e0 = blk * chunk;
    int e1 = min(E, e0 + chunk);
    for (int i = e0 + threadIdx.x; i < e1; i += TB) {
        int d = dst[i];
        int j = d >> 7;
        int slot = atomicAdd(&lcur[j], 1);
        payload[slot] = make_int2(src[i] | ((d & 127) << 17), __float_as_int(w[i]));
    }
}

// per-bucket weighted in-degree (LDS accumulate) -> dinv, selfn
__global__ __launch_bounds__(TB) void k_bstats(const int* __restrict__ bstart,
                                               const int2* __restrict__ payload,
                                               float* __restrict__ dinv,
                                               float* __restrict__ selfn, int n) {
    __shared__ float wdeg[BNODES];
    int j = blockIdx.x;
    if (threadIdx.x < BNODES) wdeg[threadIdx.x] = 0.f;
    __syncthreads();
    int b0 = bstart[j], b1 = bstart[j + 1];
    for (int i = b0 + threadIdx.x; i < b1; i += TB) {
        int2 p = payload[i];
        atomicAdd(&wdeg[(p.x >> 17) & 127], __int_as_float(p.y));
    }
    __syncthreads();
    if (threadIdx.x < BNODES) {
        int v = j * BNODES + threadIdx.x;
        if (v < n) {
            float di = rsqrtf(wdeg[threadIdx.x] + 1.0f);
            dinv[v] = di;
            selfn[v] = di * di;
        }
    }
}

// one pass of S applied to the paired channels; FIRST folds dinv[src] into the
// stored payload weight (in-place, own-bucket region only) and uses (x, 1).
template <bool FIRST>
__global__ __launch_bounds__(TB) void k_bpass(const float* __restrict__ x,
                                              const float2* __restrict__ in,
                                              const int* __restrict__ bstart,
                                              int2* __restrict__ payload,
                                              const float* __restrict__ dinv,
                                              const float* __restrict__ selfn,
                                              float2* __restrict__ out, int n) {
    __shared__ float2 sacc[BNODES];
    int j = blockIdx.x;
    if (threadIdx.x < BNODES) sacc[threadIdx.x] = make_float2(0.f, 0.f);
    __syncthreads();
    int b0 = bstart[j], b1 = bstart[j + 1];
    for (int i = b0 + threadIdx.x; i < b1; i += TB) {
        int2 p = payload[i];
        int s = p.x & 0x1FFFF;
        int ld = (p.x >> 17) & 127;
        float nw;
        float vx, vy;
        if (FIRST) {
            nw = __int_as_float(p.y) * dinv[s];
            payload[i] = make_int2(p.x, __float_as_int(nw));  // fold for passes 2-5
            vx = x[s]; vy = 1.0f;
        } else {
            nw = __int_as_float(p.y);
            float2 iv = in[s];
            vx = iv.x; vy = iv.y;
        }
        atomicAdd(&sacc[ld].x, nw * vx);
        atomicAdd(&sacc[ld].y, nw * vy);
    }
    __syncthreads();
    if (threadIdx.x < BNODES) {
        int v = j * BNODES + threadIdx.x;
        if (v < n) {
            float dv = dinv[v], sf = selfn[v];
            float ivx, ivy;
            if (FIRST) { ivx = x[v]; ivy = 1.0f; }
            else       { float2 iv = in[v]; ivx = iv.x; ivy = iv.y; }
            float2 a = sacc[threadIdx.x];
            out[v] = make_float2(fmaf(dv, a.x, sf * ivx), fmaf(dv, a.y, sf * ivy));
        }
    }
}

// ---------------- launch ----------------

extern "C" void kernel_launch(void* const* d_in, const int* in_sizes, int n_in,
                              void* d_out, int out_size, void* d_ws, size_t ws_size,
                              hipStream_t stream) {
    const float* x  = (const float*)d_in[0];
    const int*   ei = (const int*)d_in[1];     // int32: [2, E] flattened
    const float* w  = (const float*)d_in[2];
    const float* W1 = (const float*)d_in[3];  const float* b1 = (const float*)d_in[4];
    const float* W2 = (const float*)d_in[5];  const float* b2 = (const float*)d_in[6];
    const float* W3 = (const float*)d_in[7];  const float* b3 = (const float*)d_in[8];
    const float* W4 = (const float*)d_in[9];  const float* b4 = (const float*)d_in[10];
    const float* W5 = (const float*)d_in[11]; const float* b5 = (const float*)d_in[12];

    const int n = in_sizes[0];   // 100000
    const int E = in_sizes[2];   // 1600000
    const int* src = ei;
    const int* dst = ei + E;

    const int B     = (n + BNODES - 1) / BNODES;   // 782 buckets
    const int chunk = (E + CHB - 1) / CHB;         // 6250 edges per chunk block
    const int HM    = B * CHB;                     // hist matrix elements
    const int nb1   = (HM + TB - 1) / TB;          // == B (HM is B*256)

    char* ws = (char*)d_ws;
    size_t off = 0;
    auto alloc = [&](size_t bytes) -> void* {
        void* p = ws + off;
        off += (bytes + 255) & ~(size_t)255;
        return p;
    };
    int*   histmat = (int*)alloc((size_t)HM * 4);
    int*   bsum    = (int*)alloc((size_t)(B + 1) * 4);   // becomes bucket_start
    float* dinv    = (float*)alloc((size_t)n * 4);
    float* selfn   = (float*)alloc((size_t)n * 4);
    float* coef    = (float*)alloc(512 * 4);
    int2*  payload = (int2*)alloc((size_t)E * 8);
    float2* s[5];
    for (int i = 0; i < 5; ++i) s[i] = (float2*)alloc((size_t)n * 8);

    const size_t ldsB = (size_t)B * 4;

    k_hist <<<CHB, TB, ldsB, stream>>>(dst, histmat, E, B, chunk);
    k_scan1<<<nb1, TB, 0, stream>>>(histmat, bsum, HM);
    k_scan2<<<1, 1024, 0, stream>>>(bsum, nb1, E);
    k_scan3<<<nb1, TB, 0, stream>>>(histmat, bsum, HM);
    k_bplace<<<CHB, TB, ldsB, stream>>>(src, dst, w, histmat, payload, E, B, chunk);
    k_bstats<<<B, TB, 0, stream>>>(bsum, payload, dinv, selfn, n);
    k_chains<<<1, 128, 0, stream>>>(W1, b1, W2, b2, W3, b3, W4, b4, W5, coef);

    // s[k] = S^{k+1} (x, 1)
    k_bpass<true> <<<B, TB, 0, stream>>>(x, nullptr, bsum, payload, dinv, selfn, s[0], n);
    for (int k = 1; k < 5; ++k)
        k_bpass<false><<<B, TB, 0, stream>>>(nullptr, s[k - 1], bsum, payload, dinv, selfn, s[k], n);

    const int tot4 = n * 25;  // n*100 floats as float4
    k_final4<<<(tot4 + TB - 1) / TB, TB, 0, stream>>>(s[0], s[1], s[2], s[3], s[4],
                                                      coef, b5, (float4*)d_out, n);
}